// Round 5
// baseline (195.552 us; speedup 1.0000x reference)
//
#include <hip/hip_runtime.h>
#include <math.h>

// FSQuantizer v5: 16 B/lane on both heavy streams, v4 intermediate layout.
// z (32,512,4096) f32 -> zhat f32 + commit_loss + perplexity.
// kA: 512 blocks (32b x 16tt), 256 thr; lane owns 4 consecutive t (float4 loads),
//     4 waves split c 4-way; LDS combine -> full h,g per row + block stats.
// kS: 1 block finalize (BN consts, Gram, zero counts).
// kC: 512 blocks (32b x 4tt x 4cs); thread quantizes 4 rows, float4 zhat stores.
// kD: 1 block finalize scalars.

namespace {
constexpr int Cv = 512, Tv = 4096, Bv = 32;
constexpr int Nv = Bv * Tv;                       // 131072 rows
constexpr long long TOTv = (long long)Nv * Cv;    // 67108864
constexpr int NBA = 512;                          // kA blocks
constexpr int NBC = 512;                          // kC blocks
constexpr int NCP = 128;                          // commit partial slots (32b x 4tt)

// workspace layout (bytes)
constexpr size_t OFF_H  = 0;                                   // h_ws [Nv][4] f32 (2 MiB)
constexpr size_t OFF_G  = OFF_H  + (size_t)Nv * 16;            // g_ws [Nv][4] f32 (2 MiB)
constexpr size_t OFF_BS = OFF_G  + (size_t)Nv * 16;            // bs [NBA][10] f64
constexpr size_t OFF_CN = OFF_BS + (size_t)NBA * 10 * 8;       // consts [32] f64
constexpr size_t OFF_CP = OFF_CN + 32 * 8;                     // cp [NCP] f64
constexpr size_t OFF_CT = OFF_CP + (size_t)NCP * 8;            // counts [1024] u32
}

// ---- kA: stream z once (float4/lane), produce h,g per row + block stats ----
__global__ __launch_bounds__(256, 2) void fsq_kA(
    const float* __restrict__ z, const float* __restrict__ W_in,
    const float* __restrict__ b_in, const float* __restrict__ W_out,
    const float* __restrict__ b_out,
    float* __restrict__ h_ws, float* __restrict__ g_ws, double* __restrict__ bs)
{
    __shared__ float s_wi[512][4];
    __shared__ float s_wo[512][4];
    __shared__ float s_bo[512];
    __shared__ float red_h[4][256][4];   // [wave][row][e]
    __shared__ float red_g[4][256][4];
    __shared__ double s_st[4][10];

    const int tid = threadIdx.x;
    const int lane = tid & 63;
    const int w = tid >> 6;              // wave id = c-split
    const int bid = blockIdx.x;
    const int b = bid >> 4;              // 16 t-tiles per b
    const int t0 = (bid & 15) << 8;      // 256 t per block

    for (int i = tid; i < 512; i += 256) {
        *(float4*)&s_wi[i][0] = *(const float4*)(W_in + i * 4);
        s_wo[i][0] = W_out[i];
        s_wo[i][1] = W_out[512 + i];
        s_wo[i][2] = W_out[1024 + i];
        s_wo[i][3] = W_out[1536 + i];
        s_bo[i] = b_out[i];
    }
    __syncthreads();

    // main loop: wave w sweeps c = w, w+4, ..., w+508; lane owns t = t0 + lane*4 .. +3
    float h[4][4] = {}, g[4][4] = {};
    float z2 = 0.f, zb = 0.f;
    const float* zp = z + (size_t)b * Cv * Tv + t0 + lane * 4;
#pragma unroll 4
    for (int ci = 0; ci < 128; ++ci) {
        const int c = ci * 4 + w;
        const float4 zv = *(const float4*)(zp + (size_t)c * Tv);  // 1 KiB/wave-instr
        const float4 wi = *(const float4*)&s_wi[c][0];            // wave-uniform broadcast
        const float4 wo = *(const float4*)&s_wo[c][0];
        const float bo = s_bo[c];
        const float zr[4] = {zv.x, zv.y, zv.z, zv.w};
#pragma unroll
        for (int j = 0; j < 4; ++j) {
            h[j][0] = fmaf(zr[j], wi.x, h[j][0]);
            h[j][1] = fmaf(zr[j], wi.y, h[j][1]);
            h[j][2] = fmaf(zr[j], wi.z, h[j][2]);
            h[j][3] = fmaf(zr[j], wi.w, h[j][3]);
            g[j][0] = fmaf(zr[j], wo.x, g[j][0]);
            g[j][1] = fmaf(zr[j], wo.y, g[j][1]);
            g[j][2] = fmaf(zr[j], wo.z, g[j][2]);
            g[j][3] = fmaf(zr[j], wo.w, g[j][3]);
            z2 = fmaf(zr[j], zr[j], z2);
        }
        zb = fmaf((zr[0] + zr[1]) + (zr[2] + zr[3]), bo, zb);
    }

    // dump per-wave c-split partials (rows 4*lane..4*lane+3)
#pragma unroll
    for (int j = 0; j < 4; ++j) {
        *(float4*)&red_h[w][lane * 4 + j][0] = make_float4(h[j][0], h[j][1], h[j][2], h[j][3]);
        *(float4*)&red_g[w][lane * 4 + j][0] = make_float4(g[j][0], g[j][1], g[j][2], g[j][3]);
    }
    __syncthreads();

    // combine: thread tid owns row tid
    const float4 ra = *(const float4*)&red_h[0][tid][0];
    const float4 rb = *(const float4*)&red_h[1][tid][0];
    const float4 rc = *(const float4*)&red_h[2][tid][0];
    const float4 rd = *(const float4*)&red_h[3][tid][0];
    float hh[4];
    hh[0] = (ra.x + rb.x) + (rc.x + rd.x) + b_in[0];
    hh[1] = (ra.y + rb.y) + (rc.y + rd.y) + b_in[1];
    hh[2] = (ra.z + rb.z) + (rc.z + rd.z) + b_in[2];
    hh[3] = (ra.w + rb.w) + (rc.w + rd.w) + b_in[3];
    const float4 qa = *(const float4*)&red_g[0][tid][0];
    const float4 qb = *(const float4*)&red_g[1][tid][0];
    const float4 qc = *(const float4*)&red_g[2][tid][0];
    const float4 qd = *(const float4*)&red_g[3][tid][0];
    float gg[4];
    gg[0] = (qa.x + qb.x) + (qc.x + qd.x);
    gg[1] = (qa.y + qb.y) + (qc.y + qd.y);
    gg[2] = (qa.z + qb.z) + (qc.z + qd.z);
    gg[3] = (qa.w + qb.w) + (qc.w + qd.w);

    const int n = (b << 12) + t0 + tid;
    *(float4*)(h_ws + (size_t)n * 4) = make_float4(hh[0], hh[1], hh[2], hh[3]);
    *(float4*)(g_ws + (size_t)n * 4) = make_float4(gg[0], gg[1], gg[2], gg[3]);

    // block stats: Sh[4], Sh2[4], z2, zb
    double st[10];
#pragma unroll
    for (int e = 0; e < 4; ++e) {
        st[e] = (double)hh[e];
        st[4 + e] = (double)hh[e] * (double)hh[e];
    }
    st[8] = (double)z2;
    st[9] = (double)zb;
#pragma unroll
    for (int k = 0; k < 10; ++k) {
#pragma unroll
        for (int m = 1; m < 64; m <<= 1) st[k] += __shfl_xor(st[k], m, 64);
    }
    if (lane == 0) {
#pragma unroll
        for (int k = 0; k < 10; ++k) s_st[w][k] = st[k];
    }
    __syncthreads();
    if (tid < 10)
        bs[(size_t)bid * 10 + tid] = (s_st[0][tid] + s_st[1][tid]) + (s_st[2][tid] + s_st[3][tid]);
}

// ---- kS: finalize BN consts + Gram + zero counts ----
__global__ __launch_bounds__(256) void fsq_kS(
    const float* __restrict__ gamma, const float* __restrict__ beta,
    const float* __restrict__ W_out, const float* __restrict__ b_out,
    const double* __restrict__ bs, double* __restrict__ consts,
    unsigned* __restrict__ counts)
{
    __shared__ double sbuf[15][256];
    const int tid = threadIdx.x;

    for (int i = tid; i < 1000; i += 256) counts[i] = 0;

    double a[10] = {};
    for (int r = tid; r < NBA; r += 256) {
        const double* p = bs + (size_t)r * 10;
#pragma unroll
        for (int k = 0; k < 10; ++k) a[k] += p[k];
    }
#pragma unroll
    for (int k = 0; k < 10; ++k) sbuf[k][tid] = a[k];
    __syncthreads();
    for (int s = 128; s > 0; s >>= 1) {
        if (tid < s) {
#pragma unroll
            for (int k = 0; k < 10; ++k) sbuf[k][tid] += sbuf[k][tid + s];
        }
        __syncthreads();
    }
    double tot[10];
    if (tid == 0) {
#pragma unroll
        for (int k = 0; k < 10; ++k) tot[k] = sbuf[k][0];
    }
    __syncthreads();

    // Gram of W_out rows + v + s0
    double gr[15] = {};
    for (int c = tid; c < 512; c += 256) {
        const double w0 = (double)W_out[c], w1 = (double)W_out[512 + c];
        const double w2 = (double)W_out[1024 + c], w3 = (double)W_out[1536 + c];
        const double bb = (double)b_out[c];
        gr[0] += w0 * w0; gr[1] += w0 * w1; gr[2] += w0 * w2; gr[3] += w0 * w3;
        gr[4] += w1 * w1; gr[5] += w1 * w2; gr[6] += w1 * w3;
        gr[7] += w2 * w2; gr[8] += w2 * w3; gr[9] += w3 * w3;
        gr[10] += w0 * bb; gr[11] += w1 * bb; gr[12] += w2 * bb; gr[13] += w3 * bb;
        gr[14] += bb * bb;
    }
#pragma unroll
    for (int k = 0; k < 15; ++k) sbuf[k][tid] = gr[k];
    __syncthreads();
    for (int s = 128; s > 0; s >>= 1) {
        if (tid < s) {
#pragma unroll
            for (int k = 0; k < 15; ++k) sbuf[k][tid] += sbuf[k][tid + s];
        }
        __syncthreads();
    }
    if (tid == 0) {
        const double Ninv = 1.0 / (double)Nv;
#pragma unroll
        for (int e = 0; e < 4; ++e) {
            const double mu = tot[e] * Ninv;
            const double var = tot[4 + e] * Ninv - mu * mu;   // biased, matches jnp.var
            const double sc = (double)gamma[e] / sqrt(var + 1e-5);
            consts[e] = sc;
            consts[4 + e] = (double)beta[e] - mu * sc;
        }
        consts[8] = tot[8];   // sum z^2
        consts[9] = tot[9];   // sum z.b_out
#pragma unroll
        for (int k = 0; k < 15; ++k) consts[16 + k] = sbuf[k][0];
        constexpr double hl0 = (8.0 - 1.0) * (1.0 - 1e-3) / 2.0;
        consts[31] = tan(0.5 / hl0);
    }
}

// ---- kC: quantize 4 rows/thread + histogram + commit + float4 zhat stores ----
__global__ __launch_bounds__(256, 2) void fsq_kC(
    const float* __restrict__ W_out, const float* __restrict__ b_out,
    const float* __restrict__ h_ws, const float* __restrict__ g_ws,
    const double* __restrict__ consts, unsigned* __restrict__ counts,
    double* __restrict__ cp, float* __restrict__ out)
{
    __shared__ float s_wo[128][4];
    __shared__ float s_bo[128];
    __shared__ double s_cp[4];

    const int tid = threadIdx.x;
    const int lane = tid & 63;
    const int w = tid >> 6;
    const int bid = blockIdx.x;
    const int b = bid >> 4;              // 16 blocks per b (4 tt x 4 cs)
    const int tt = (bid >> 2) & 3;
    const int cs = bid & 3;
    const int c0 = cs << 7;              // 128-c slab
    const int t0 = tt << 10;             // 1024 t per block
    const int n0 = (b << 12) + t0;       // row base

    if (tid < 128) {
        const int c = c0 + tid;
        s_wo[tid][0] = W_out[c];
        s_wo[tid][1] = W_out[512 + c];
        s_wo[tid][2] = W_out[1024 + c];
        s_wo[tid][3] = W_out[1536 + c];
        s_bo[tid] = b_out[c];
    }
    __syncthreads();

    const double sc0 = consts[0], sc1 = consts[1], sc2 = consts[2], sc3 = consts[3];
    const double bi0 = consts[4], bi1 = consts[5], bi2 = consts[6], bi3 = consts[7];
    const double shift0 = consts[31];
    constexpr double hl0 = (8.0 - 1.0) * (1.0 - 1e-3) / 2.0;   // 3.4965
    constexpr double hl1 = (5.0 - 1.0) * (1.0 - 1e-3) / 2.0;   // 1.998

    // quantize 4 consecutive rows (n0 + 4*tid .. +3)
    float zn[4][4];
    double qsum = 0.0;
#pragma unroll
    for (int j = 0; j < 4; ++j) {
        const int n = n0 + tid * 4 + j;
        const float4 hv = *(const float4*)(h_ws + (size_t)n * 4);  // 64 B/lane contiguous
        const double hn0 = fma((double)hv.x, sc0, bi0);
        const double hn1 = fma((double)hv.y, sc1, bi1);
        const double hn2 = fma((double)hv.z, sc2, bi2);
        const double hn3 = fma((double)hv.w, sc3, bi3);
        const double r0 = rint(tanh(hn0 + shift0) * hl0 - 0.5);   // [-4,3]
        const double r1 = rint(tanh(hn1) * hl1);                  // [-2,2]
        const double r2 = rint(tanh(hn2) * hl1);
        const double r3 = rint(tanh(hn3) * hl1);
        const double zd0 = r0 * 0.25, zd1 = r1 * 0.5, zd2 = r2 * 0.5, zd3 = r3 * 0.5;
        zn[j][0] = (float)zd0; zn[j][1] = (float)zd1;
        zn[j][2] = (float)zd2; zn[j][3] = (float)zd3;
        if (cs == 0) {
            const int code = ((int)r0 + 4) + ((int)r1 + 2) * 8 + ((int)r2 + 2) * 40
                           + ((int)r3 + 2) * 200;
            atomicAdd(&counts[code], 1u);
            const float4 gv = *(const float4*)(g_ws + (size_t)n * 4);
            const double cg = zd0 * (double)gv.x + zd1 * (double)gv.y
                            + zd2 * (double)gv.z + zd3 * (double)gv.w;
            double q = consts[16 + 14]
                     + 2.0 * (zd0 * consts[16 + 10] + zd1 * consts[16 + 11]
                            + zd2 * consts[16 + 12] + zd3 * consts[16 + 13])
                     + zd0 * zd0 * consts[16 + 0] + zd1 * zd1 * consts[16 + 4]
                     + zd2 * zd2 * consts[16 + 7] + zd3 * zd3 * consts[16 + 9]
                     + 2.0 * (zd0 * zd1 * consts[16 + 1] + zd0 * zd2 * consts[16 + 2]
                            + zd0 * zd3 * consts[16 + 3] + zd1 * zd2 * consts[16 + 5]
                            + zd1 * zd3 * consts[16 + 6] + zd2 * zd3 * consts[16 + 8]);
            qsum += q - 2.0 * cg;
        }
    }

    // block reduce qsum (uniform; only cs==0 blocks have nonzero)
#pragma unroll
    for (int m = 1; m < 64; m <<= 1) qsum += __shfl_xor(qsum, m, 64);
    if (lane == 0) s_cp[w] = qsum;
    __syncthreads();
    if (tid == 0 && cs == 0)
        cp[b * 4 + tt] = (s_cp[0] + s_cp[1]) + (s_cp[2] + s_cp[3]);

    // store zhat slab: float4/lane, 1 KiB/wave-instr
    float* op = out + ((size_t)b * Cv + c0) * Tv + t0 + tid * 4;
#pragma unroll 4
    for (int i = 0; i < 128; ++i) {
        const float4 wo = *(const float4*)&s_wo[i][0];
        const float bo = s_bo[i];
        float4 o;
        o.x = fmaf(zn[0][0], wo.x, fmaf(zn[0][1], wo.y,
              fmaf(zn[0][2], wo.z, fmaf(zn[0][3], wo.w, bo))));
        o.y = fmaf(zn[1][0], wo.x, fmaf(zn[1][1], wo.y,
              fmaf(zn[1][2], wo.z, fmaf(zn[1][3], wo.w, bo))));
        o.z = fmaf(zn[2][0], wo.x, fmaf(zn[2][1], wo.y,
              fmaf(zn[2][2], wo.z, fmaf(zn[2][3], wo.w, bo))));
        o.w = fmaf(zn[3][0], wo.x, fmaf(zn[3][1], wo.y,
              fmaf(zn[3][2], wo.z, fmaf(zn[3][3], wo.w, bo))));
        *(float4*)(op + (size_t)i * Tv) = o;
    }
}

// ---- kD: finalize scalars ----
__global__ __launch_bounds__(256) void fsq_kD(
    const double* __restrict__ cp, const double* __restrict__ consts,
    const unsigned* __restrict__ counts, float* __restrict__ out, int out_size)
{
    __shared__ double r1[256], r2[256];
    const int tid = threadIdx.x;
    double c_ = (tid < NCP) ? cp[tid] : 0.0;
    double pl = 0.0;
    for (int i = tid; i < 1000; i += 256) {
        const double em = (double)counts[i] / (double)Nv;
        pl += em * log(em + 1e-10);
    }
    r1[tid] = c_; r2[tid] = pl;
    __syncthreads();
    for (int s = 128; s > 0; s >>= 1) {
        if (tid < s) { r1[tid] += r1[tid + s]; r2[tid] += r2[tid + s]; }
        __syncthreads();
    }
    if (tid == 0) {
        const double commit = (consts[8] - 2.0 * consts[9] + r1[0]) / (double)TOTv;
        out[out_size - 2] = (float)commit;
        out[out_size - 1] = (float)exp(-r2[0]);
    }
}

extern "C" void kernel_launch(void* const* d_in, const int* in_sizes, int n_in,
                              void* d_out, int out_size, void* d_ws, size_t ws_size,
                              hipStream_t stream) {
    const float* z     = (const float*)d_in[0];
    const float* W_in  = (const float*)d_in[1];
    const float* b_in  = (const float*)d_in[2];
    const float* gamma = (const float*)d_in[3];
    const float* beta  = (const float*)d_in[4];
    const float* W_out = (const float*)d_in[5];
    const float* b_out = (const float*)d_in[6];
    float* out = (float*)d_out;

    char* ws = (char*)d_ws;
    float*    h_ws   = (float*)(ws + OFF_H);
    float*    g_ws   = (float*)(ws + OFF_G);
    double*   bs     = (double*)(ws + OFF_BS);
    double*   consts = (double*)(ws + OFF_CN);
    double*   cp     = (double*)(ws + OFF_CP);
    unsigned* counts = (unsigned*)(ws + OFF_CT);

    fsq_kA<<<NBA, 256, 0, stream>>>(z, W_in, b_in, W_out, b_out, h_ws, g_ws, bs);
    fsq_kS<<<1, 256, 0, stream>>>(gamma, beta, W_out, b_out, bs, consts, counts);
    fsq_kC<<<NBC, 256, 0, stream>>>(W_out, b_out, h_ws, g_ws, consts, counts, cp, out);
    fsq_kD<<<1, 256, 0, stream>>>(cp, consts, counts, out, out_size);
}